// Round 6
// baseline (404.270 us; speedup 1.0000x reference)
//
#include <hip/hip_runtime.h>
#include <math.h>

#define N 4096

typedef float f32x4 __attribute__((ext_vector_type(4)));

// ---------------------------------------------------------------------------
// One row of matvec, computed by the whole 256-thread block.
// out[p] = act(dot(W[p], x) + b[p]); mode 0: tanh; mode 1: y=v, out=sigmoid.
// W is streamed read-once -> NT loads (protect x in L2).
// ---------------------------------------------------------------------------
__device__ __forceinline__ void mv_row(const float* __restrict__ W,
                                       const float* __restrict__ b,
                                       const float* __restrict__ x,
                                       float* __restrict__ out,
                                       float* __restrict__ y_out,
                                       int p, int mode, float* red) {
    const int tid = threadIdx.x;
    const f32x4* xv = reinterpret_cast<const f32x4*>(x);
    const f32x4* Wr = reinterpret_cast<const f32x4*>(W + (size_t)p * N);

    float acc = 0.0f;
#pragma unroll
    for (int i = 0; i < 4; ++i) {
        const int j = tid + i * 256;
        f32x4 w4 = __builtin_nontemporal_load(Wr + j);
        f32x4 x4 = xv[j];
        acc += w4.x * x4.x + w4.y * x4.y + w4.z * x4.z + w4.w * x4.w;
    }
#pragma unroll
    for (int off = 32; off > 0; off >>= 1)
        acc += __shfl_down(acc, off, 64);
    if ((tid & 63) == 0) red[tid >> 6] = acc;
    __syncthreads();
    if (tid == 0) {
        const float v = red[0] + red[1] + red[2] + red[3] + b[p];
        if (mode == 0) {
            out[p] = tanhf(v);
        } else {
            y_out[p] = v;
            out[p]   = 1.0f / (1.0f + expf(-v));
        }
    }
    __syncthreads();   // red[] reused by the next row
}

// ---------------------------------------------------------------------------
// One 4-q Hebbian group. H streamed read-once -> NT loads; outW write-once ->
// NT stores. pre/post stay L2-resident.
// ---------------------------------------------------------------------------
__device__ __forceinline__ void hebb_group(const float* __restrict__ H,
                                           const float* __restrict__ pre,
                                           const float* __restrict__ post,
                                           float* __restrict__ outW, int idx) {
    const int p  = idx >> 10;
    const int q0 = (idx & 1023) << 2;

    const size_t base = ((size_t)p * N + q0) * 5;
    const f32x4* h4   = reinterpret_cast<const f32x4*>(H + base);
    f32x4 v0 = __builtin_nontemporal_load(h4 + 0);
    f32x4 v1 = __builtin_nontemporal_load(h4 + 1);
    f32x4 v2 = __builtin_nontemporal_load(h4 + 2);
    f32x4 v3 = __builtin_nontemporal_load(h4 + 3);
    f32x4 v4 = __builtin_nontemporal_load(h4 + 4);

    const float po = post[p];
    const f32x4 pr = *reinterpret_cast<const f32x4*>(pre + q0);

    f32x4 o;
    o.x = 2.0f * v0.x * (v0.y * pr.x * po + v0.z * pr.x + v0.w * po + v1.x);
    o.y = 2.0f * v1.y * (v1.z * pr.y * po + v1.w * pr.y + v2.x * po + v2.y);
    o.z = 2.0f * v2.z * (v2.w * pr.z * po + v3.x * pr.z + v3.y * po + v3.z);
    o.w = 2.0f * v3.w * (v4.x * pr.w * po + v4.y * pr.w + v4.z * po + v4.w);

    __builtin_nontemporal_store(o, reinterpret_cast<f32x4*>(outW + (size_t)p * N + q0));
}

// ---------------------------------------------------------------------------
// Standalone matvec (layer 0): one block per row.
// ---------------------------------------------------------------------------
__global__ __launch_bounds__(256) void mv_kernel(const float* __restrict__ W,
                                                 const float* __restrict__ b,
                                                 const float* __restrict__ x,
                                                 float* __restrict__ out,
                                                 float* __restrict__ y_out,
                                                 int mode) {
    __shared__ float red[4];
    mv_row(W, b, x, out, y_out, blockIdx.x, mode, red);
}

// ---------------------------------------------------------------------------
// Fused dispatch: blocks [0,2048) run matvec layer L+1 (2 rows each),
// blocks [2048, 18432) run hebb layer L (independent of the matvec).
// ---------------------------------------------------------------------------
__global__ __launch_bounds__(256) void mv_hebb(const float* __restrict__ W,
                                               const float* __restrict__ b,
                                               const float* __restrict__ xin,
                                               float* __restrict__ mv_out,
                                               float* __restrict__ y_out,
                                               int mode,
                                               const float* __restrict__ H,
                                               const float* __restrict__ pre,
                                               const float* __restrict__ post,
                                               float* __restrict__ outW) {
    __shared__ float red[4];
    if (blockIdx.x < 2048) {
        mv_row(W, b, xin, mv_out, y_out, blockIdx.x * 2,     mode, red);
        mv_row(W, b, xin, mv_out, y_out, blockIdx.x * 2 + 1, mode, red);
    } else {
        const int idx = (blockIdx.x - 2048) * 256 + threadIdx.x;
        hebb_group(H, pre, post, outW, idx);
    }
}

// ---------------------------------------------------------------------------
// Standalone hebb (layer 2).
// ---------------------------------------------------------------------------
__global__ __launch_bounds__(256) void hebb_kernel(const float* __restrict__ H,
                                                   const float* __restrict__ pre,
                                                   const float* __restrict__ post,
                                                   float* __restrict__ outW) {
    const int idx = blockIdx.x * 256 + threadIdx.x;
    hebb_group(H, pre, post, outW, idx);
}

// ---------------------------------------------------------------------------
// d_in: x, W0, b0, H0, W1, b1, H1, W2, b2, H2
// d_out: y (4096) | new_W0 | new_W1 | new_W2   (all f32)
// Schedule: mv0 -> [mv1 || hebb0] -> [mv2 || hebb1] -> hebb2
// ---------------------------------------------------------------------------
extern "C" void kernel_launch(void* const* d_in, const int* in_sizes, int n_in,
                              void* d_out, int out_size, void* d_ws, size_t ws_size,
                              hipStream_t stream) {
    const float* x  = (const float*)d_in[0];
    const float* W0 = (const float*)d_in[1];
    const float* b0 = (const float*)d_in[2];
    const float* H0 = (const float*)d_in[3];
    const float* W1 = (const float*)d_in[4];
    const float* b1 = (const float*)d_in[5];
    const float* H1 = (const float*)d_in[6];
    const float* W2 = (const float*)d_in[7];
    const float* b2 = (const float*)d_in[8];
    const float* H2 = (const float*)d_in[9];

    float* out = (float*)d_out;
    float* y   = out;                          // 4096
    float* oW0 = out + N;                      // 4096*4096
    float* oW1 = oW0 + (size_t)N * N;
    float* oW2 = oW1 + (size_t)N * N;

    float* s  = (float*)d_ws;
    float* s1 = s;          // tanh layer-0 output
    float* s2 = s + N;      // tanh layer-1 output
    float* s3 = s + 2 * N;  // sigmoid(y)

    // D0: mv0 (s1 = tanh(W0 x + b0))
    hipLaunchKernelGGL(mv_kernel, dim3(N), dim3(256), 0, stream,
                       W0, b0, x, s1, (float*)nullptr, 0);

    // D1: mv1 (s2) || hebb0 (oW0 from H0, pre=x, post=s1)
    hipLaunchKernelGGL(mv_hebb, dim3(18432), dim3(256), 0, stream,
                       W1, b1, s1, s2, (float*)nullptr, 0,
                       H0, x, s1, oW0);

    // D2: mv2 (s3, y) || hebb1 (oW1 from H1, pre=s1, post=s2)
    hipLaunchKernelGGL(mv_hebb, dim3(18432), dim3(256), 0, stream,
                       W2, b2, s2, s3, y, 1,
                       H1, s1, s2, oW1);

    // D3: hebb2 (oW2 from H2, pre=s2, post=s3)
    hipLaunchKernelGGL(hebb_kernel, dim3(16384), dim3(256), 0, stream,
                       H2, s2, s3, oW2);
}

// Round 7
// 277.771 us; speedup vs baseline: 1.4554x; 1.4554x over previous
//
#include <hip/hip_runtime.h>
#include <math.h>

#define N 4096

typedef float f32x4 __attribute__((ext_vector_type(4)));

// ---------------------------------------------------------------------------
// One row of matvec, computed by the whole 256-thread block.
// out[p] = act(dot(W[p], x) + b[p]); mode 0: tanh; mode 1: y=v, out=sigmoid.
// ---------------------------------------------------------------------------
__device__ __forceinline__ void mv_row(const float* __restrict__ W,
                                       const float* __restrict__ b,
                                       const float* __restrict__ x,
                                       float* __restrict__ out,
                                       float* __restrict__ y_out,
                                       int p, int mode, float* red) {
    const int tid = threadIdx.x;
    const f32x4* xv = reinterpret_cast<const f32x4*>(x);
    const f32x4* Wr = reinterpret_cast<const f32x4*>(W + (size_t)p * N);

    float acc = 0.0f;
#pragma unroll
    for (int i = 0; i < 4; ++i) {
        const int j = tid + i * 256;
        f32x4 w4 = Wr[j];
        f32x4 x4 = xv[j];
        acc += w4.x * x4.x + w4.y * x4.y + w4.z * x4.z + w4.w * x4.w;
    }
#pragma unroll
    for (int off = 32; off > 0; off >>= 1)
        acc += __shfl_down(acc, off, 64);
    if ((tid & 63) == 0) red[tid >> 6] = acc;
    __syncthreads();
    if (tid == 0) {
        const float v = red[0] + red[1] + red[2] + red[3] + b[p];
        if (mode == 0) {
            out[p] = tanhf(v);
        } else {
            y_out[p] = v;
            out[p]   = 1.0f / (1.0f + expf(-v));
        }
    }
    __syncthreads();   // red[] reused by the next row
}

// ---------------------------------------------------------------------------
// One 4-q Hebbian group (plain cached loads/stores — NT proven harmful R3/R6).
// ---------------------------------------------------------------------------
__device__ __forceinline__ void hebb_group(const float* __restrict__ H,
                                           const float* __restrict__ pre,
                                           const float* __restrict__ post,
                                           float* __restrict__ outW, int idx) {
    const int p  = idx >> 10;
    const int q0 = (idx & 1023) << 2;

    const size_t base = ((size_t)p * N + q0) * 5;
    const f32x4* h4   = reinterpret_cast<const f32x4*>(H + base);
    f32x4 v0 = h4[0];
    f32x4 v1 = h4[1];
    f32x4 v2 = h4[2];
    f32x4 v3 = h4[3];
    f32x4 v4 = h4[4];

    const float po = post[p];
    const f32x4 pr = *reinterpret_cast<const f32x4*>(pre + q0);

    f32x4 o;
    o.x = 2.0f * v0.x * (v0.y * pr.x * po + v0.z * pr.x + v0.w * po + v1.x);
    o.y = 2.0f * v1.y * (v1.z * pr.y * po + v1.w * pr.y + v2.x * po + v2.y);
    o.z = 2.0f * v2.z * (v2.w * pr.z * po + v3.x * pr.z + v3.y * po + v3.z);
    o.w = 2.0f * v3.w * (v4.x * pr.w * po + v4.y * pr.w + v4.z * po + v4.w);

    *reinterpret_cast<f32x4*>(outW + (size_t)p * N + q0) = o;
}

// ---------------------------------------------------------------------------
// Uniform 2048-block dispatch: each block does mv_nrows matvec rows, then
// hebb_iters grid-strided hebb chunks. All blocks co-resident (8/CU) -> no
// scheduling rounds, no tail stragglers.
// ---------------------------------------------------------------------------
__global__ __launch_bounds__(256) void fused_kernel(const float* __restrict__ W,
                                                    const float* __restrict__ b,
                                                    const float* __restrict__ xin,
                                                    float* __restrict__ mv_out,
                                                    float* __restrict__ y_out,
                                                    int mode, int mv_nrows,
                                                    const float* __restrict__ H,
                                                    const float* __restrict__ pre,
                                                    const float* __restrict__ post,
                                                    float* __restrict__ outW,
                                                    int hebb_iters) {
    __shared__ float red[4];

    for (int r = 0; r < mv_nrows; ++r)
        mv_row(W, b, xin, mv_out, y_out, blockIdx.x * mv_nrows + r, mode, red);

    for (int k = 0; k < hebb_iters; ++k) {
        const int idx = (blockIdx.x * 256 + threadIdx.x) + k * (2048 * 256);
        hebb_group(H, pre, post, outW, idx);
    }
}

// ---------------------------------------------------------------------------
// d_in: x, W0, b0, H0, W1, b1, H1, W2, b2, H2
// d_out: y (4096) | new_W0 | new_W1 | new_W2   (all f32)
// Schedule: mv0 -> [mv1 + hebb0] -> [mv2 + hebb1] -> hebb2, all 2048 blocks.
// ---------------------------------------------------------------------------
extern "C" void kernel_launch(void* const* d_in, const int* in_sizes, int n_in,
                              void* d_out, int out_size, void* d_ws, size_t ws_size,
                              hipStream_t stream) {
    const float* x  = (const float*)d_in[0];
    const float* W0 = (const float*)d_in[1];
    const float* b0 = (const float*)d_in[2];
    const float* H0 = (const float*)d_in[3];
    const float* W1 = (const float*)d_in[4];
    const float* b1 = (const float*)d_in[5];
    const float* H1 = (const float*)d_in[6];
    const float* W2 = (const float*)d_in[7];
    const float* b2 = (const float*)d_in[8];
    const float* H2 = (const float*)d_in[9];

    float* out = (float*)d_out;
    float* y   = out;                          // 4096
    float* oW0 = out + N;                      // 4096*4096
    float* oW1 = oW0 + (size_t)N * N;
    float* oW2 = oW1 + (size_t)N * N;

    float* s  = (float*)d_ws;
    float* s1 = s;          // tanh layer-0 output
    float* s2 = s + N;      // tanh layer-1 output
    float* s3 = s + 2 * N;  // sigmoid(y)

    const dim3 grid(2048), block(256);

    // D0: mv0 only (2 rows/block)
    hipLaunchKernelGGL(fused_kernel, grid, block, 0, stream,
                       W0, b0, x, s1, (float*)nullptr, 0, 2,
                       (const float*)nullptr, (const float*)nullptr,
                       (const float*)nullptr, (float*)nullptr, 0);

    // D1: mv1 (2 rows/block) + hebb0 (8 chunks/block)
    hipLaunchKernelGGL(fused_kernel, grid, block, 0, stream,
                       W1, b1, s1, s2, (float*)nullptr, 0, 2,
                       H0, x, s1, oW0, 8);

    // D2: mv2 (2 rows/block, sigmoid+y) + hebb1
    hipLaunchKernelGGL(fused_kernel, grid, block, 0, stream,
                       W2, b2, s2, s3, y, 1, 2,
                       H1, s1, s2, oW1, 8);

    // D3: hebb2 only
    hipLaunchKernelGGL(fused_kernel, grid, block, 0, stream,
                       (const float*)nullptr, (const float*)nullptr,
                       (const float*)nullptr, (float*)nullptr, (float*)nullptr, 0, 0,
                       H2, s2, s3, oW2, 8);
}

// Round 8
// 257.957 us; speedup vs baseline: 1.5672x; 1.0768x over previous
//
#include <hip/hip_runtime.h>
#include <math.h>

#define N 4096

typedef float f32x4 __attribute__((ext_vector_type(4)));

// ---------------------------------------------------------------------------
// One row of matvec, computed by the whole 256-thread block.
// out[p] = act(dot(W[p], x) + b[p]); mode 0: tanh; mode 1: y=v, out=sigmoid.
// red = 4-float scratch (carved from the block's shared buffer).
// ---------------------------------------------------------------------------
__device__ __forceinline__ void mv_row(const float* __restrict__ W,
                                       const float* __restrict__ b,
                                       const float* __restrict__ x,
                                       float* __restrict__ out,
                                       float* __restrict__ y_out,
                                       int p, int mode, float* red) {
    const int tid = threadIdx.x;
    const f32x4* xv = reinterpret_cast<const f32x4*>(x);
    const f32x4* Wr = reinterpret_cast<const f32x4*>(W + (size_t)p * N);

    float acc = 0.0f;
#pragma unroll
    for (int i = 0; i < 4; ++i) {
        const int j = tid + i * 256;
        f32x4 w4 = Wr[j];
        f32x4 x4 = xv[j];
        acc += w4.x * x4.x + w4.y * x4.y + w4.z * x4.z + w4.w * x4.w;
    }
#pragma unroll
    for (int off = 32; off > 0; off >>= 1)
        acc += __shfl_down(acc, off, 64);
    if ((tid & 63) == 0) red[tid >> 6] = acc;
    __syncthreads();
    if (tid == 0) {
        const float v = red[0] + red[1] + red[2] + red[3] + b[p];
        if (mode == 0) {
            out[p] = tanhf(v);
        } else {
            y_out[p] = v;
            out[p]   = 1.0f / (1.0f + expf(-v));
        }
    }
    __syncthreads();   // red[] reused by the next row
}

// ---------------------------------------------------------------------------
// One block's Hebbian chunk (1024 structs = 20 KB of H), LDS-staged:
//  - 5 perfectly-coalesced global f32x4 loads per thread (stride 4 KB between
//    instrs, 16 B between lanes) -> LDS           [kills 5x line re-touch]
//  - barrier, then each thread reads its 20 floats from LDS at stride 80 B
//    (balanced across all 32 banks) and computes 4 outputs.
// ---------------------------------------------------------------------------
__device__ __forceinline__ void hebb_block(const float* __restrict__ H,
                                           const float* __restrict__ pre,
                                           const float* __restrict__ post,
                                           float* __restrict__ outW,
                                           int bidx, f32x4* lds4) {
    const int tid = threadIdx.x;

    const f32x4* Hg = reinterpret_cast<const f32x4*>(H) + (size_t)bidx * 1280;
#pragma unroll
    for (int k = 0; k < 5; ++k)
        lds4[k * 256 + tid] = Hg[k * 256 + tid];
    __syncthreads();

    const int idx = bidx * 256 + tid;   // 4-struct group index
    const int p   = idx >> 10;
    const int q0  = (idx & 1023) << 2;

    f32x4 v0 = lds4[5 * tid + 0];
    f32x4 v1 = lds4[5 * tid + 1];
    f32x4 v2 = lds4[5 * tid + 2];
    f32x4 v3 = lds4[5 * tid + 3];
    f32x4 v4 = lds4[5 * tid + 4];

    const float po = post[p];
    const f32x4 pr = *reinterpret_cast<const f32x4*>(pre + q0);

    f32x4 o;
    o.x = 2.0f * v0.x * (v0.y * pr.x * po + v0.z * pr.x + v0.w * po + v1.x);
    o.y = 2.0f * v1.y * (v1.z * pr.y * po + v1.w * pr.y + v2.x * po + v2.y);
    o.z = 2.0f * v2.z * (v2.w * pr.z * po + v3.x * pr.z + v3.y * po + v3.z);
    o.w = 2.0f * v3.w * (v4.x * pr.w * po + v4.y * pr.w + v4.z * po + v4.w);

    *reinterpret_cast<f32x4*>(outW + (size_t)p * N + q0) = o;
}

// ---------------------------------------------------------------------------
// Standalone matvec (layer 0): one block per row.
// ---------------------------------------------------------------------------
__global__ __launch_bounds__(256) void mv_kernel(const float* __restrict__ W,
                                                 const float* __restrict__ b,
                                                 const float* __restrict__ x,
                                                 float* __restrict__ out,
                                                 float* __restrict__ y_out,
                                                 int mode) {
    __shared__ f32x4 lds4[1280];   // only first 16 B used (reduce scratch)
    mv_row(W, b, x, out, y_out, blockIdx.x, mode, reinterpret_cast<float*>(lds4));
}

// ---------------------------------------------------------------------------
// Fused dispatch: blocks [0,2048) run matvec layer L+1 (2 rows each),
// blocks [2048, 18432) run hebb layer L (independent of the matvec).
// ---------------------------------------------------------------------------
__global__ __launch_bounds__(256) void mv_hebb(const float* __restrict__ W,
                                               const float* __restrict__ b,
                                               const float* __restrict__ xin,
                                               float* __restrict__ mv_out,
                                               float* __restrict__ y_out,
                                               int mode,
                                               const float* __restrict__ H,
                                               const float* __restrict__ pre,
                                               const float* __restrict__ post,
                                               float* __restrict__ outW) {
    __shared__ f32x4 lds4[1280];   // 20 KB: hebb staging / mv reduce scratch
    if (blockIdx.x < 2048) {
        float* red = reinterpret_cast<float*>(lds4);
        mv_row(W, b, xin, mv_out, y_out, blockIdx.x * 2,     mode, red);
        mv_row(W, b, xin, mv_out, y_out, blockIdx.x * 2 + 1, mode, red);
    } else {
        hebb_block(H, pre, post, outW, blockIdx.x - 2048, lds4);
    }
}

// ---------------------------------------------------------------------------
// Standalone hebb (layer 2).
// ---------------------------------------------------------------------------
__global__ __launch_bounds__(256) void hebb_kernel(const float* __restrict__ H,
                                                   const float* __restrict__ pre,
                                                   const float* __restrict__ post,
                                                   float* __restrict__ outW) {
    __shared__ f32x4 lds4[1280];
    hebb_block(H, pre, post, outW, blockIdx.x, lds4);
}

// ---------------------------------------------------------------------------
// d_in: x, W0, b0, H0, W1, b1, H1, W2, b2, H2
// d_out: y (4096) | new_W0 | new_W1 | new_W2   (all f32)
// Schedule: mv0 -> [mv1 || hebb0] -> [mv2 || hebb1] -> hebb2
// ---------------------------------------------------------------------------
extern "C" void kernel_launch(void* const* d_in, const int* in_sizes, int n_in,
                              void* d_out, int out_size, void* d_ws, size_t ws_size,
                              hipStream_t stream) {
    const float* x  = (const float*)d_in[0];
    const float* W0 = (const float*)d_in[1];
    const float* b0 = (const float*)d_in[2];
    const float* H0 = (const float*)d_in[3];
    const float* W1 = (const float*)d_in[4];
    const float* b1 = (const float*)d_in[5];
    const float* H1 = (const float*)d_in[6];
    const float* W2 = (const float*)d_in[7];
    const float* b2 = (const float*)d_in[8];
    const float* H2 = (const float*)d_in[9];

    float* out = (float*)d_out;
    float* y   = out;                          // 4096
    float* oW0 = out + N;                      // 4096*4096
    float* oW1 = oW0 + (size_t)N * N;
    float* oW2 = oW1 + (size_t)N * N;

    float* s  = (float*)d_ws;
    float* s1 = s;          // tanh layer-0 output
    float* s2 = s + N;      // tanh layer-1 output
    float* s3 = s + 2 * N;  // sigmoid(y)

    // D0: mv0 (s1 = tanh(W0 x + b0))
    hipLaunchKernelGGL(mv_kernel, dim3(N), dim3(256), 0, stream,
                       W0, b0, x, s1, (float*)nullptr, 0);

    // D1: mv1 (s2) || hebb0 (oW0 from H0, pre=x, post=s1)
    hipLaunchKernelGGL(mv_hebb, dim3(18432), dim3(256), 0, stream,
                       W1, b1, s1, s2, (float*)nullptr, 0,
                       H0, x, s1, oW0);

    // D2: mv2 (s3, y) || hebb1 (oW1 from H1, pre=s1, post=s2)
    hipLaunchKernelGGL(mv_hebb, dim3(18432), dim3(256), 0, stream,
                       W2, b2, s2, s3, y, 1,
                       H1, s1, s2, oW1);

    // D3: hebb2 (oW2 from H2, pre=s2, post=s3)
    hipLaunchKernelGGL(hebb_kernel, dim3(16384), dim3(256), 0, stream,
                       H2, s2, s3, oW2);
}

// Round 9
// 253.084 us; speedup vs baseline: 1.5974x; 1.0193x over previous
//
#include <hip/hip_runtime.h>
#include <math.h>

#define N 4096

typedef float f32x4 __attribute__((ext_vector_type(4)));

// ---------------------------------------------------------------------------
// One 4-q Hebbian group (R1 body — plain cached loads; NT harmful R3/R6;
// LDS staging neutral R8).
// ---------------------------------------------------------------------------
__device__ __forceinline__ void hebb_group(const float* __restrict__ H,
                                           const float* __restrict__ pre,
                                           const float* __restrict__ post,
                                           float* __restrict__ outW, int idx) {
    const int p  = idx >> 10;
    const int q0 = (idx & 1023) << 2;

    const size_t base = ((size_t)p * N + q0) * 5;
    const f32x4* h4   = reinterpret_cast<const f32x4*>(H + base);
    f32x4 v0 = h4[0];
    f32x4 v1 = h4[1];
    f32x4 v2 = h4[2];
    f32x4 v3 = h4[3];
    f32x4 v4 = h4[4];

    const float po = post[p];
    const f32x4 pr = *reinterpret_cast<const f32x4*>(pre + q0);

    f32x4 o;
    o.x = 2.0f * v0.x * (v0.y * pr.x * po + v0.z * pr.x + v0.w * po + v1.x);
    o.y = 2.0f * v1.y * (v1.z * pr.y * po + v1.w * pr.y + v2.x * po + v2.y);
    o.z = 2.0f * v2.z * (v2.w * pr.z * po + v3.x * pr.z + v3.y * po + v3.z);
    o.w = 2.0f * v3.w * (v4.x * pr.w * po + v4.y * pr.w + v4.z * po + v4.w);

    *reinterpret_cast<f32x4*>(outW + (size_t)p * N + q0) = o;
}

// ---------------------------------------------------------------------------
// Standalone matvec (layer 0): one block per row.
// ---------------------------------------------------------------------------
__global__ __launch_bounds__(256) void mv_kernel(const float* __restrict__ W,
                                                 const float* __restrict__ b,
                                                 const float* __restrict__ x,
                                                 float* __restrict__ out,
                                                 float* __restrict__ y_out,
                                                 int mode) {
    const int tid = threadIdx.x;
    const int p   = blockIdx.x;
    __shared__ float red[4];

    const f32x4* xv = reinterpret_cast<const f32x4*>(x);
    const f32x4* Wr = reinterpret_cast<const f32x4*>(W + (size_t)p * N);

    float acc = 0.0f;
#pragma unroll
    for (int i = 0; i < 4; ++i) {
        const int j = tid + i * 256;
        f32x4 w4 = Wr[j];
        f32x4 x4 = xv[j];
        acc += w4.x * x4.x + w4.y * x4.y + w4.z * x4.z + w4.w * x4.w;
    }
#pragma unroll
    for (int off = 32; off > 0; off >>= 1)
        acc += __shfl_down(acc, off, 64);
    if ((tid & 63) == 0) red[tid >> 6] = acc;
    __syncthreads();
    if (tid == 0) {
        const float v = red[0] + red[1] + red[2] + red[3] + b[p];
        if (mode == 0) {
            out[p] = tanhf(v);
        } else {
            y_out[p] = v;
            out[p]   = 1.0f / (1.0f + expf(-v));
        }
    }
}

// ---------------------------------------------------------------------------
// Fused dispatch, load-interleaved (NOT phase-serialized like R7):
// all 16384 blocks run one hebb chunk; blocks < 4096 ALSO compute one mv row.
// The mv W/x loads are issued BEFORE the hebb loads' results are consumed, so
// all ~13 loads/thread are in flight together; the dot+reduce runs under the
// hebb store latency. Same bytes as R5, zero dedicated mv blocks.
// ---------------------------------------------------------------------------
__global__ __launch_bounds__(256) void mv_hebb(const float* __restrict__ W,
                                               const float* __restrict__ b,
                                               const float* __restrict__ xin,
                                               float* __restrict__ mv_out,
                                               float* __restrict__ y_out,
                                               int mode,
                                               const float* __restrict__ H,
                                               const float* __restrict__ pre,
                                               const float* __restrict__ post,
                                               float* __restrict__ outW) {
    const int tid  = threadIdx.x;
    const int bidx = blockIdx.x;
    const bool do_mv = (bidx < 4096);
    __shared__ float red[4];

    // --- issue mv loads first (consumed first, shortest live range) ---
    float acc = 0.0f;
    if (do_mv) {
        const f32x4* xv = reinterpret_cast<const f32x4*>(xin);
        const f32x4* Wr = reinterpret_cast<const f32x4*>(W + (size_t)bidx * N);
#pragma unroll
        for (int i = 0; i < 4; ++i) {
            const int j = tid + i * 256;
            f32x4 w4 = Wr[j];
            f32x4 x4 = xv[j];
            acc += w4.x * x4.x + w4.y * x4.y + w4.z * x4.z + w4.w * x4.w;
        }
    }

    // --- hebb chunk (loads issue while dot's waits retire) ---
    hebb_group(H, pre, post, outW, bidx * 256 + tid);

    // --- finish mv: reduce + activation ---
    if (do_mv) {
#pragma unroll
        for (int off = 32; off > 0; off >>= 1)
            acc += __shfl_down(acc, off, 64);
        if ((tid & 63) == 0) red[tid >> 6] = acc;
        __syncthreads();
        if (tid == 0) {
            const float v = red[0] + red[1] + red[2] + red[3] + b[bidx];
            if (mode == 0) {
                mv_out[bidx] = tanhf(v);
            } else {
                y_out[bidx]  = v;
                mv_out[bidx] = 1.0f / (1.0f + expf(-v));
            }
        }
    }
}

// ---------------------------------------------------------------------------
// Standalone hebb (layer 2).
// ---------------------------------------------------------------------------
__global__ __launch_bounds__(256) void hebb_kernel(const float* __restrict__ H,
                                                   const float* __restrict__ pre,
                                                   const float* __restrict__ post,
                                                   float* __restrict__ outW) {
    hebb_group(H, pre, post, outW, blockIdx.x * 256 + threadIdx.x);
}

// ---------------------------------------------------------------------------
// d_in: x, W0, b0, H0, W1, b1, H1, W2, b2, H2
// d_out: y (4096) | new_W0 | new_W1 | new_W2   (all f32)
// Schedule: mv0 -> [mv1 & hebb0 interleaved] -> [mv2 & hebb1] -> hebb2
// ---------------------------------------------------------------------------
extern "C" void kernel_launch(void* const* d_in, const int* in_sizes, int n_in,
                              void* d_out, int out_size, void* d_ws, size_t ws_size,
                              hipStream_t stream) {
    const float* x  = (const float*)d_in[0];
    const float* W0 = (const float*)d_in[1];
    const float* b0 = (const float*)d_in[2];
    const float* H0 = (const float*)d_in[3];
    const float* W1 = (const float*)d_in[4];
    const float* b1 = (const float*)d_in[5];
    const float* H1 = (const float*)d_in[6];
    const float* W2 = (const float*)d_in[7];
    const float* b2 = (const float*)d_in[8];
    const float* H2 = (const float*)d_in[9];

    float* out = (float*)d_out;
    float* y   = out;                          // 4096
    float* oW0 = out + N;                      // 4096*4096
    float* oW1 = oW0 + (size_t)N * N;
    float* oW2 = oW1 + (size_t)N * N;

    float* s  = (float*)d_ws;
    float* s1 = s;          // tanh layer-0 output
    float* s2 = s + N;      // tanh layer-1 output
    float* s3 = s + 2 * N;  // sigmoid(y)

    // D0: mv0 (s1 = tanh(W0 x + b0))
    hipLaunchKernelGGL(mv_kernel, dim3(N), dim3(256), 0, stream,
                       W0, b0, x, s1, (float*)nullptr, 0);

    // D1: hebb0 (oW0 from H0, pre=x, post=s1) with mv1 interleaved in blocks<4096
    hipLaunchKernelGGL(mv_hebb, dim3(16384), dim3(256), 0, stream,
                       W1, b1, s1, s2, (float*)nullptr, 0,
                       H0, x, s1, oW0);

    // D2: hebb1 (oW1 from H1, pre=s1, post=s2) with mv2 interleaved
    hipLaunchKernelGGL(mv_hebb, dim3(16384), dim3(256), 0, stream,
                       W2, b2, s2, s3, y, 1,
                       H1, s1, s2, oW1);

    // D3: hebb2 (oW2 from H2, pre=s2, post=s3)
    hipLaunchKernelGGL(hebb_kernel, dim3(16384), dim3(256), 0, stream,
                       H2, s2, s3, oW2);
}